// Round 2
// baseline (361.337 us; speedup 1.0000x reference)
//
#include <hip/hip_runtime.h>

typedef unsigned short u16;
typedef unsigned int u32;
typedef __attribute__((ext_vector_type(8))) short bf16x8;
typedef __attribute__((ext_vector_type(4))) float f32x4;

__device__ __forceinline__ u16 f2bf(float f) {
    u32 u = __float_as_uint(f);
    u += 0x7fffu + ((u >> 16) & 1u);   // RNE
    return (u16)(u >> 16);
}

__device__ __forceinline__ void llds16(void* l, const void* g) {
    __builtin_amdgcn_global_load_lds(
        (const __attribute__((address_space(1))) u32*)g,
        (__attribute__((address_space(3))) u32*)l, 16, 0, 0);
}

// ---- prep: x NCHW f32 -> NHWC bf16 (LDS transpose, 32c x 32w tiles) --------
__global__ void prep_x(const float* __restrict__ x, u16* __restrict__ xt) {
    __shared__ float xl[32 * 33];
    int b = blockIdx.x;             // 64 n * 32 h * 8 cb
    int n = b >> 8, rem = b & 255;
    int h = rem >> 3, c0 = (rem & 7) << 5;
    int t = threadIdx.x;
    int cl = t >> 5, w = t & 31;
#pragma unroll
    for (int i = 0; i < 4; ++i) {
        int c = c0 + i * 8 + cl;
        xl[(i * 8 + cl) * 33 + w] = x[(n * 256 + c) * 1024 + h * 32 + w];
    }
    __syncthreads();
    int wo = t >> 3, k = t & 7;
    ushort4 o;
    o.x = f2bf(xl[(k * 4 + 0) * 33 + wo]);
    o.y = f2bf(xl[(k * 4 + 1) * 33 + wo]);
    o.z = f2bf(xl[(k * 4 + 2) * 33 + wo]);
    o.w = f2bf(xl[(k * 4 + 3) * 33 + wo]);
    *(ushort4*)&xt[((n * 32 + h) * 32 + wo) * 256 + c0 + k * 4] = o;
}

// ---- prep: w [co][ci][3][3] f32 -> Wt [p][co][ci] bf16, + BN fold + zp -----
__global__ void prep_w(const float* __restrict__ w1, const float* __restrict__ w2,
                       u16* __restrict__ W1t, u16* __restrict__ W2t,
                       const float* __restrict__ g1, const float* __restrict__ b1,
                       const float* __restrict__ rm1, const float* __restrict__ rv1,
                       const float* __restrict__ g2, const float* __restrict__ b2,
                       const float* __restrict__ rm2, const float* __restrict__ rv2,
                       float* __restrict__ sc, float* __restrict__ zp) {
    int idx = blockIdx.x * 256 + threadIdx.x;        // 0..65535 = (co,ci)
    const float* src = blockIdx.y ? w2 : w1;
    u16* dst = blockIdx.y ? W2t : W1t;
    const float* s = src + idx * 9;
    int co = idx >> 8, ci = idx & 255;
#pragma unroll
    for (int p = 0; p < 9; ++p)
        dst[p * 65536 + co * 256 + ci] = f2bf(s[p]);
    if (blockIdx.x == 0 && blockIdx.y == 0) {
        int t = threadIdx.x;
        float s1 = g1[t] * rsqrtf(rv1[t] + 1e-5f);
        sc[t]       = s1;
        sc[256 + t] = b1[t] - rm1[t] * s1;
        float s2 = g2[t] * rsqrtf(rv2[t] + 1e-5f);
        sc[512 + t] = s2;
        sc[768 + t] = b2[t] - rm2[t] * s2;
        zp[t] = 0.0f;   // 1KB zero page for OOB-row global_load_lds
    }
}

// ---- main: fused conv3x3 + BN (+skip) + ReLU via MFMA implicit GEMM --------
// Block: 64 c_out x (16h x 32w). 4 waves; each wave 64co x (4h x 32w) =
// 4x8 tiles of 16x16x32 MFMA -> 12 ds_read_b128 per 32 MFMA (was 8 per 16).
// A [9][64][32] and B [18][34][32] staged via global_load_lds width=16;
// wp=0/33 columns permanent zeros (w halo), OOB h rows -> zero page.
__global__ __launch_bounds__(256, 2) void conv_mfma(
    const u16* __restrict__ Xt,    // NHWC bf16 input
    const u16* __restrict__ Wt,    // [9][256][256] bf16
    const float* __restrict__ sv,  // scale[256]
    const float* __restrict__ tv,  // shift[256]
    const float* __restrict__ skip,// NCHW f32 (stage2) or null
    u16* __restrict__ ybf,         // NHWC bf16 out (stage1)
    float* __restrict__ yf,        // NCHW f32 out (stage2)
    const u16* __restrict__ zp, int stage)
{
    __shared__ alignas(16) u16 ldsA[9 * 64 * 32];   // 36864 B
    __shared__ alignas(16) u16 ldsB[18 * 34 * 32];  // 39168 B

    int t = threadIdx.x;
    int wv = t >> 6, lane = t & 63;
    int q = lane >> 4, n16 = lane & 15, q8 = q * 8;
    int co0 = blockIdx.x << 6, h0 = blockIdx.y << 4, nb = blockIdx.z;

    // zero the w-halo columns once (never overwritten by staging)
    {
        ushort4 z; z.x = 0; z.y = 0; z.z = 0; z.w = 0;
        for (int i = t; i < 288; i += 256) {
            int hh = i >> 4, side = (i >> 3) & 1, o8 = i & 7;
            *(ushort4*)&ldsB[hh * 1088 + side * 1056 + o8 * 4] = z;
        }
    }

    f32x4 acc[4][8] = {};

    for (int kc = 0; kc < 256; kc += 32) {
        // stage A: 36 x 1KB wave-chunks, 9 per wave
#pragma unroll
        for (int i = 0; i < 9; ++i) {
            int g = wv * 9 + i;
            int p = g >> 2, co = ((g & 3) << 4) + (lane >> 2), ci = (lane & 3) << 3;
            const u16* gp = Wt + (p << 16) + ((co0 + co) << 8) + kc + ci;
            llds16(&ldsA[g << 9], gp);
        }
        // stage B: 36 x 1KB wave-chunks (18 rows x 2 halves, interior wp=1..32)
#pragma unroll
        for (int j = 0; j < 9; ++j) {
            int g = wv * 9 + j;
            int hh = g >> 1, half = g & 1;
            int w = (half << 4) + (lane >> 2), ci = (lane & 3) << 3;
            int hin = h0 - 1 + hh;
            const u16* gp = (hin >= 0 && hin < 32)
                          ? (Xt + ((nb * 32 + hin) * 32 + w) * 256 + kc + ci)
                          : (zp + lane * 8);
            llds16(&ldsB[hh * 1088 + 32 + (half << 9)], gp);
        }
        asm volatile("s_waitcnt vmcnt(0)" ::: "memory");
        __syncthreads();

#pragma unroll
        for (int p = 0; p < 9; ++p) {
            const int kh = p / 3, kw = p % 3;
            bf16x8 aF[4], bF[8];
#pragma unroll
            for (int mt = 0; mt < 4; ++mt)
                aF[mt] = *(const bf16x8*)&ldsA[(p << 11) + (((mt << 4) + n16) << 5) + q8];
#pragma unroll
            for (int nt = 0; nt < 8; ++nt) {
                int hi = (wv << 2) + (nt >> 1) + kh;
                int wp = ((nt & 1) << 4) + n16 + kw;
                bF[nt] = *(const bf16x8*)&ldsB[hi * 1088 + wp * 32 + q8];
            }
#pragma unroll
            for (int mt = 0; mt < 4; ++mt)
#pragma unroll
                for (int nt = 0; nt < 8; ++nt)
                    acc[mt][nt] = __builtin_amdgcn_mfma_f32_16x16x32_bf16(
                        aF[mt], bF[nt], acc[mt][nt], 0, 0, 0);
        }
        __syncthreads();
    }

    // epilogue: C/D layout col=lane&15 (spatial w), row=q*4+reg (c_out)
    if (stage == 1) {
#pragma unroll
        for (int mt = 0; mt < 4; ++mt) {
            int cb = co0 + (mt << 4) + (q << 2);
            f32x4 ss = *(const f32x4*)&sv[cb];
            f32x4 tt = *(const f32x4*)&tv[cb];
#pragma unroll
            for (int nt = 0; nt < 8; ++nt) {
                int h = h0 + (wv << 2) + (nt >> 1), w = ((nt & 1) << 4) + n16;
                ushort4 o;
                o.x = f2bf(fmaxf(acc[mt][nt][0] * ss[0] + tt[0], 0.f));
                o.y = f2bf(fmaxf(acc[mt][nt][1] * ss[1] + tt[1], 0.f));
                o.z = f2bf(fmaxf(acc[mt][nt][2] * ss[2] + tt[2], 0.f));
                o.w = f2bf(fmaxf(acc[mt][nt][3] * ss[3] + tt[3], 0.f));
                *(ushort4*)&ybf[(((nb << 5) + h) * 32 + w) * 256 + cb] = o;
            }
        }
    } else {
#pragma unroll
        for (int mt = 0; mt < 4; ++mt) {
            int cb = co0 + (mt << 4) + (q << 2);
            f32x4 ss = *(const f32x4*)&sv[cb];
            f32x4 tt = *(const f32x4*)&tv[cb];
#pragma unroll
            for (int nt = 0; nt < 8; ++nt) {
                int h = h0 + (wv << 2) + (nt >> 1), w = ((nt & 1) << 4) + n16;
#pragma unroll
                for (int j = 0; j < 4; ++j) {
                    int idx = (((nb << 8) + cb + j) << 10) + (h << 5) + w;
                    yf[idx] = fmaxf(acc[mt][nt][j] * ss[j] + tt[j] + skip[idx], 0.f);
                }
            }
        }
    }
}

extern "C" void kernel_launch(void* const* d_in, const int* in_sizes, int n_in,
                              void* d_out, int out_size, void* d_ws, size_t ws_size,
                              hipStream_t stream) {
    const float* x   = (const float*)d_in[0];
    const float* w1  = (const float*)d_in[1];
    const float* g1  = (const float*)d_in[2];
    const float* b1  = (const float*)d_in[3];
    const float* rm1 = (const float*)d_in[4];
    const float* rv1 = (const float*)d_in[5];
    const float* w2  = (const float*)d_in[6];
    const float* g2  = (const float*)d_in[7];
    const float* b2  = (const float*)d_in[8];
    const float* rm2 = (const float*)d_in[9];
    const float* rv2 = (const float*)d_in[10];

    char* ws = (char*)d_ws;
    // ws layout (bytes): XT 0..32MB, H1 32MB..64MB, W1t, W2t, scales, zeropage
    u16*  XT  = (u16*)(ws);
    u16*  H1  = (u16*)(ws + 33554432);
    u16*  W1t = (u16*)(ws + 67108864);
    u16*  W2t = (u16*)(ws + 68288512);
    float* sc = (float*)(ws + 69468160);   // s1|t1|s2|t2, 256 f32 each
    u16*  zpg = (u16*)(ws + 69472256);     // 1KB zeros
    if (ws_size < 69473280) return;        // workspace too small — bail

    prep_x<<<16384, 256, 0, stream>>>(x, XT);
    prep_w<<<dim3(256, 2), 256, 0, stream>>>(w1, w2, W1t, W2t,
                                             g1, b1, rm1, rv1, g2, b2, rm2, rv2,
                                             sc, (float*)zpg);

    dim3 grid(4, 2, 64);  // c_out tiles x h tiles x n
    conv_mfma<<<grid, 256, 0, stream>>>(XT, W1t, sc, sc + 256, nullptr,
                                        H1, nullptr, zpg, 1);
    conv_mfma<<<grid, 256, 0, stream>>>(H1, W2t, sc + 512, sc + 768, x,
                                        nullptr, (float*)d_out, zpg, 2);
}

// Round 4
// 274.629 us; speedup vs baseline: 1.3157x; 1.3157x over previous
//
#include <hip/hip_runtime.h>

typedef unsigned short u16;
typedef unsigned int u32;
typedef __attribute__((ext_vector_type(8))) short bf16x8;
typedef __attribute__((ext_vector_type(4))) float f32x4;

__device__ __forceinline__ u16 f2bf(float f) {
    u32 u = __float_as_uint(f);
    u += 0x7fffu + ((u >> 16) & 1u);   // RNE
    return (u16)(u >> 16);
}

__device__ __forceinline__ void llds16(void* l, const void* g) {
    __builtin_amdgcn_global_load_lds(
        (const __attribute__((address_space(1))) u32*)g,
        (__attribute__((address_space(3))) u32*)l, 16, 0, 0);
}

// ---- prep (single dispatch): x NCHW f32 -> NHWC bf16, w -> [p][co][ci] bf16,
//      BN fold (s=g*rsqrt(v+eps), t=b-m*s), 2KB zero page ---------------------
__global__ void prep(const float* __restrict__ x, u16* __restrict__ xt,
                     const float* __restrict__ w1, const float* __restrict__ w2,
                     u16* __restrict__ W1t, u16* __restrict__ W2t,
                     const float* __restrict__ g1, const float* __restrict__ b1,
                     const float* __restrict__ rm1, const float* __restrict__ rv1,
                     const float* __restrict__ g2, const float* __restrict__ b2,
                     const float* __restrict__ rm2, const float* __restrict__ rv2,
                     float* __restrict__ sc, u32* __restrict__ zp) {
    int t = threadIdx.x;
    int b = blockIdx.x;
    if (b < 16384) {
        // x transpose: 64 n * 32 h * 8 cb blocks; 32c x 32w tile via LDS
        __shared__ float xl[32 * 33];
        int n = b >> 8, rem = b & 255;
        int h = rem >> 3, c0 = (rem & 7) << 5;
        int cl = t >> 5, w = t & 31;
#pragma unroll
        for (int i = 0; i < 4; ++i) {
            int c = c0 + i * 8 + cl;
            xl[(i * 8 + cl) * 33 + w] = x[(n * 256 + c) * 1024 + h * 32 + w];
        }
        __syncthreads();
        int wo = t >> 3, k = t & 7;
        ushort4 o;
        o.x = f2bf(xl[(k * 4 + 0) * 33 + wo]);
        o.y = f2bf(xl[(k * 4 + 1) * 33 + wo]);
        o.z = f2bf(xl[(k * 4 + 2) * 33 + wo]);
        o.w = f2bf(xl[(k * 4 + 3) * 33 + wo]);
        *(ushort4*)&xt[((n * 32 + h) * 32 + wo) * 256 + c0 + k * 4] = o;
    } else {
        int bb = b - 16384;                     // 0..511
        int idx = (bb & 255) * 256 + t;         // (co,ci) pair
        const float* src = (bb >> 8) ? w2 : w1;
        u16* dst = (bb >> 8) ? W2t : W1t;
        const float* s = src + idx * 9;
        int co = idx >> 8, ci = idx & 255;
#pragma unroll
        for (int p = 0; p < 9; ++p)
            dst[p * 65536 + co * 256 + ci] = f2bf(s[p]);
        if (bb == 0) {
            float s1 = g1[t] * rsqrtf(rv1[t] + 1e-5f);
            sc[t]       = s1;
            sc[256 + t] = b1[t] - rm1[t] * s1;
            float s2 = g2[t] * rsqrtf(rv2[t] + 1e-5f);
            sc[512 + t] = s2;
            sc[768 + t] = b2[t] - rm2[t] * s2;
            zp[t] = 0u;            // 2KB zero page (512 u32)
            zp[t + 256] = 0u;
        }
    }
}

// ---- main: fused conv3x3 + BN (+skip) + ReLU via MFMA implicit GEMM --------
// Block: 64 c_out x (8h x 32w), 4 waves, wave = 64co x 64sp = 4x4 16x16x32.
// LDS A: fragment-major [p][mt][lane]*16B  -> identity ds_read (0 conflicts).
// LDS B: [hi 0..10][wp 0..33][q 0..3][8ci] -> balanced banks; halo slots
// (wp=0/33, OOB h) sourced from a zero page inside the same staging pass.
// Inner loop: kw outer, 8 bF loaded once per kw, reused across 3 kh
// -> 60 ds_read_b128 per kc (was 72 + conflicts).
__global__ __launch_bounds__(256, 2) void conv_mfma(
    const u16* __restrict__ Xt,    // NHWC bf16 input
    const u16* __restrict__ Wt,    // [9][256][256] bf16
    const float* __restrict__ sv,  // scale[256]
    const float* __restrict__ tv,  // shift[256]
    const float* __restrict__ skip,// NCHW f32 (stage2) or null
    u16* __restrict__ ybf,         // NHWC bf16 out (stage1)
    float* __restrict__ yf,        // NCHW f32 out (stage2)
    const u16* __restrict__ zp, int stage)
{
    __shared__ alignas(16) u16 ldsA[9 * 4 * 64 * 8];   // 36 chunks = 36864 B
    __shared__ alignas(16) u16 ldsB[22 * 64 * 8];      // 22 chunks = 22528 B

    int t = threadIdx.x;
    int wv = t >> 6, lane = t & 63;
    int q = lane >> 4, n16 = lane & 15;
    int co0 = blockIdx.x << 6, h0 = blockIdx.y << 3, nb = blockIdx.z;

    // ---- precompute staging source pointers (kc added in-loop) ----
    // A: 9 chunks/wave; chunk g = wv*9+i -> (p = g>>2, mt = g&3);
    // lane fetches Wt[p][co0 + mt*16 + (lane&15)][ (lane>>4)*8 + kc ]
    const u16* aSrc[9];
#pragma unroll
    for (int i = 0; i < 9; ++i) {
        int g = wv * 9 + i;
        int p = g >> 2, mt = g & 3;
        aSrc[i] = Wt + (p << 16) + ((co0 + (mt << 4) + n16) << 8) + (q << 3);
    }
    // B: 22 chunks total; chunk g2 = wv*6+j (skip g2>=22); slot s = g2*64+lane;
    // s -> hi = s/136, wp = (s%136)>>2, qq = s&3; halo/OOB -> zero page.
    const u16* bSrc[6];
#pragma unroll
    for (int j = 0; j < 6; ++j) {
        int g2 = wv * 6 + j;
        if (g2 < 22) {
            int s = g2 * 64 + lane;
            int hi = s / 136, rem = s - hi * 136;
            int wp = rem >> 2, qq = rem & 3;
            int hin = h0 - 1 + hi;
            bool v = (wp >= 1) && (wp <= 32) && (hin >= 0) && (hin < 32);
            bSrc[j] = v ? (Xt + (((nb << 5) + hin) * 32 + (wp - 1)) * 256 + (qq << 3))
                        : (zp + lane * 8);      // zp is 2KB: +kc stays in-bounds
        } else {
            bSrc[j] = zp + lane * 8;
        }
    }

    f32x4 acc[4][4] = {};

    for (int kc = 0; kc < 256; kc += 32) {
#pragma unroll
        for (int i = 0; i < 9; ++i)
            llds16(&ldsA[(wv * 9 + i) << 9], aSrc[i] + kc);
#pragma unroll
        for (int j = 0; j < 6; ++j) {
            int g2 = wv * 6 + j;
            if (g2 < 22) llds16(&ldsB[g2 << 9], bSrc[j] + kc);
        }
        asm volatile("s_waitcnt vmcnt(0)" ::: "memory");
        __syncthreads();

#pragma unroll
        for (int kw = 0; kw < 3; ++kw) {
            bf16x8 bFr[4][2];
#pragma unroll
            for (int r = 0; r < 4; ++r)
#pragma unroll
                for (int half = 0; half < 2; ++half) {
                    int hi = (wv << 1) + r;
                    int wp = (half << 4) + n16 + kw;
                    bFr[r][half] = *(const bf16x8*)
                        &ldsB[(hi * 136 + (wp << 2) + q) << 3];
                }
#pragma unroll
            for (int kh = 0; kh < 3; ++kh) {
                int p = kh * 3 + kw;
                bf16x8 aF[4];
#pragma unroll
                for (int mt = 0; mt < 4; ++mt)
                    aF[mt] = *(const bf16x8*)&ldsA[((p << 8) + (mt << 6) + lane) << 3];
#pragma unroll
                for (int mt = 0; mt < 4; ++mt)
#pragma unroll
                    for (int nt = 0; nt < 4; ++nt)
                        acc[mt][nt] = __builtin_amdgcn_mfma_f32_16x16x32_bf16(
                            aF[mt], bFr[(nt >> 1) + kh][nt & 1], acc[mt][nt], 0, 0, 0);
            }
        }
        __syncthreads();
    }

    // epilogue: C/D layout col=lane&15 (spatial w), row=q*4+reg (c_out)
    if (stage == 1) {
#pragma unroll
        for (int mt = 0; mt < 4; ++mt) {
            int cb = co0 + (mt << 4) + (q << 2);
            f32x4 ss = *(const f32x4*)&sv[cb];
            f32x4 tt = *(const f32x4*)&tv[cb];
#pragma unroll
            for (int nt = 0; nt < 4; ++nt) {
                int h = h0 + (wv << 1) + (nt >> 1), w = ((nt & 1) << 4) + n16;
                ushort4 o;
                o.x = f2bf(fmaxf(acc[mt][nt][0] * ss[0] + tt[0], 0.f));
                o.y = f2bf(fmaxf(acc[mt][nt][1] * ss[1] + tt[1], 0.f));
                o.z = f2bf(fmaxf(acc[mt][nt][2] * ss[2] + tt[2], 0.f));
                o.w = f2bf(fmaxf(acc[mt][nt][3] * ss[3] + tt[3], 0.f));
                *(ushort4*)&ybf[(((nb << 5) + h) * 32 + w) * 256 + cb] = o;
            }
        }
    } else {
#pragma unroll
        for (int mt = 0; mt < 4; ++mt) {
            int cb = co0 + (mt << 4) + (q << 2);
            f32x4 ss = *(const f32x4*)&sv[cb];
            f32x4 tt = *(const f32x4*)&tv[cb];
#pragma unroll
            for (int nt = 0; nt < 4; ++nt) {
                int h = h0 + (wv << 1) + (nt >> 1), w = ((nt & 1) << 4) + n16;
#pragma unroll
                for (int j = 0; j < 4; ++j) {
                    int idx = (((nb << 8) + cb + j) << 10) + (h << 5) + w;
                    yf[idx] = fmaxf(acc[mt][nt][j] * ss[j] + tt[j] + skip[idx], 0.f);
                }
            }
        }
    }
}

extern "C" void kernel_launch(void* const* d_in, const int* in_sizes, int n_in,
                              void* d_out, int out_size, void* d_ws, size_t ws_size,
                              hipStream_t stream) {
    const float* x   = (const float*)d_in[0];
    const float* w1  = (const float*)d_in[1];
    const float* g1  = (const float*)d_in[2];
    const float* b1  = (const float*)d_in[3];
    const float* rm1 = (const float*)d_in[4];
    const float* rv1 = (const float*)d_in[5];
    const float* w2  = (const float*)d_in[6];
    const float* g2  = (const float*)d_in[7];
    const float* b2  = (const float*)d_in[8];
    const float* rm2 = (const float*)d_in[9];
    const float* rv2 = (const float*)d_in[10];

    char* ws = (char*)d_ws;
    u16*  XT  = (u16*)(ws);                    // 32 MB NHWC bf16 x
    u16*  H1  = (u16*)(ws + 33554432);         // 32 MB NHWC bf16 intermediate
    u16*  W1t = (u16*)(ws + 67108864);         // 1.18 MB
    u16*  W2t = (u16*)(ws + 68288512);         // 1.18 MB
    float* sc = (float*)(ws + 69468160);       // s1|t1|s2|t2, 256 f32 each
    u32*  zpg = (u32*)(ws + 69472256);         // 2 KB zeros
    if (ws_size < 69474304) return;            // workspace too small — bail

    prep<<<16896, 256, 0, stream>>>(x, XT, w1, w2, W1t, W2t,
                                    g1, b1, rm1, rv1, g2, b2, rm2, rv2,
                                    sc, zpg);

    dim3 grid(4, 4, 64);  // c_out tiles x h tiles x n
    conv_mfma<<<grid, 256, 0, stream>>>(XT, W1t, sc, sc + 256, nullptr,
                                        H1, nullptr, (const u16*)zpg, 1);
    conv_mfma<<<grid, 256, 0, stream>>>(H1, W2t, sc + 512, sc + 768, x,
                                        nullptr, (float*)d_out, (const u16*)zpg, 2);
}

// Round 5
// 268.271 us; speedup vs baseline: 1.3469x; 1.0237x over previous
//
#include <hip/hip_runtime.h>

typedef unsigned short u16;
typedef unsigned int u32;
typedef __attribute__((ext_vector_type(8))) short bf16x8;
typedef __attribute__((ext_vector_type(4))) float f32x4;

__device__ __forceinline__ u16 f2bf(float f) {
    u32 u = __float_as_uint(f);
    u += 0x7fffu + ((u >> 16) & 1u);   // RNE
    return (u16)(u >> 16);
}

__device__ __forceinline__ void llds16(void* l, const void* g) {
    __builtin_amdgcn_global_load_lds(
        (const __attribute__((address_space(1))) u32*)g,
        (__attribute__((address_space(3))) u32*)l, 16, 0, 0);
}

// ---- prep (single dispatch): x NCHW f32 -> NHWC bf16, w -> [p][co][ci] bf16,
//      BN fold (s=g*rsqrt(v+eps), t=b-m*s), 2KB zero page ---------------------
__global__ void prep(const float* __restrict__ x, u16* __restrict__ xt,
                     const float* __restrict__ w1, const float* __restrict__ w2,
                     u16* __restrict__ W1t, u16* __restrict__ W2t,
                     const float* __restrict__ g1, const float* __restrict__ b1,
                     const float* __restrict__ rm1, const float* __restrict__ rv1,
                     const float* __restrict__ g2, const float* __restrict__ b2,
                     const float* __restrict__ rm2, const float* __restrict__ rv2,
                     float* __restrict__ sc, u32* __restrict__ zp) {
    int t = threadIdx.x;
    int b = blockIdx.x;
    if (b < 16384) {
        // x transpose: 64 n * 32 h * 8 cb blocks; 32c x 32w tile via LDS
        __shared__ float xl[32 * 33];
        int n = b >> 8, rem = b & 255;
        int h = rem >> 3, c0 = (rem & 7) << 5;
        int cl = t >> 5, w = t & 31;
#pragma unroll
        for (int i = 0; i < 4; ++i) {
            int c = c0 + i * 8 + cl;
            xl[(i * 8 + cl) * 33 + w] = x[(n * 256 + c) * 1024 + h * 32 + w];
        }
        __syncthreads();
        int wo = t >> 3, k = t & 7;
        ushort4 o;
        o.x = f2bf(xl[(k * 4 + 0) * 33 + wo]);
        o.y = f2bf(xl[(k * 4 + 1) * 33 + wo]);
        o.z = f2bf(xl[(k * 4 + 2) * 33 + wo]);
        o.w = f2bf(xl[(k * 4 + 3) * 33 + wo]);
        *(ushort4*)&xt[((n * 32 + h) * 32 + wo) * 256 + c0 + k * 4] = o;
    } else {
        int bb = b - 16384;                     // 0..511
        int idx = (bb & 255) * 256 + t;         // (co,ci) pair
        const float* src = (bb >> 8) ? w2 : w1;
        u16* dst = (bb >> 8) ? W2t : W1t;
        const float* s = src + idx * 9;
        int co = idx >> 8, ci = idx & 255;
#pragma unroll
        for (int p = 0; p < 9; ++p)
            dst[p * 65536 + co * 256 + ci] = f2bf(s[p]);
        if (bb == 0) {
            float s1 = g1[t] * rsqrtf(rv1[t] + 1e-5f);
            sc[t]       = s1;
            sc[256 + t] = b1[t] - rm1[t] * s1;
            float s2 = g2[t] * rsqrtf(rv2[t] + 1e-5f);
            sc[512 + t] = s2;
            sc[768 + t] = b2[t] - rm2[t] * s2;
            zp[t] = 0u;            // 2KB zero page (512 u32)
            zp[t + 256] = 0u;
        }
    }
}

// ---- main: fused conv3x3 + BN (+skip) + ReLU via MFMA implicit GEMM --------
// Block: 64 c_out x (8h x 32w), 4 waves, wave = 64co x 64sp = 4x4 16x16x32.
// XCD swizzle: bid%8 pins the XCD slot; the 4 co-tiles sharing one spatial
// band run on the SAME XCD back-to-back -> X staging hits that XCD's L2
// (~200cy) instead of HBM (~900cy), shortening the per-kc barrier drain.
__global__ __launch_bounds__(256, 2) void conv_mfma(
    const u16* __restrict__ Xt,    // NHWC bf16 input
    const u16* __restrict__ Wt,    // [9][256][256] bf16
    const float* __restrict__ sv,  // scale[256]
    const float* __restrict__ tv,  // shift[256]
    const float* __restrict__ skip,// NCHW f32 (stage2) or null
    u16* __restrict__ ybf,         // NHWC bf16 out (stage1)
    float* __restrict__ yf,        // NCHW f32 out (stage2)
    const u16* __restrict__ zp, int stage)
{
    __shared__ alignas(16) u16 ldsA[9 * 4 * 64 * 8];   // 36 chunks = 36864 B
    __shared__ alignas(16) u16 ldsB[22 * 64 * 8];      // 22 chunks = 22528 B

    int t = threadIdx.x;
    int wv = t >> 6, lane = t & 63;
    int q = lane >> 4, n16 = lane & 15;

    // XCD-aware decode: k = bid&7 (XCD slot), co varies within a 32-bid window
    int bid = blockIdx.x;
    int co_t = (bid >> 3) & 3;
    int sp   = ((bid >> 5) << 3) | (bid & 7);   // 0..255 spatial tile
    int h_t  = sp & 3, nb = sp >> 2;
    int co0 = co_t << 6, h0 = h_t << 3;

    // ---- precompute staging source pointers (kc added in-loop) ----
    // A: 9 chunks/wave; chunk g = wv*9+i -> (p = g>>2, mt = g&3);
    // lane fetches Wt[p][co0 + mt*16 + (lane&15)][ (lane>>4)*8 + kc ]
    const u16* aSrc[9];
#pragma unroll
    for (int i = 0; i < 9; ++i) {
        int g = wv * 9 + i;
        int p = g >> 2, mt = g & 3;
        aSrc[i] = Wt + (p << 16) + ((co0 + (mt << 4) + n16) << 8) + (q << 3);
    }
    // B: 22 chunks total; chunk g2 = wv*6+j (skip g2>=22); slot s = g2*64+lane;
    // s -> hi = s/136, wp = (s%136)>>2, qq = s&3; halo/OOB -> zero page.
    const u16* bSrc[6];
#pragma unroll
    for (int j = 0; j < 6; ++j) {
        int g2 = wv * 6 + j;
        if (g2 < 22) {
            int s = g2 * 64 + lane;
            int hi = s / 136, rem = s - hi * 136;
            int wp = rem >> 2, qq = rem & 3;
            int hin = h0 - 1 + hi;
            bool v = (wp >= 1) && (wp <= 32) && (hin >= 0) && (hin < 32);
            bSrc[j] = v ? (Xt + (((nb << 5) + hin) * 32 + (wp - 1)) * 256 + (qq << 3))
                        : (zp + lane * 8);      // zp is 2KB: +kc stays in-bounds
        } else {
            bSrc[j] = zp + lane * 8;
        }
    }

    f32x4 acc[4][4] = {};

    for (int kc = 0; kc < 256; kc += 32) {
#pragma unroll
        for (int i = 0; i < 9; ++i)
            llds16(&ldsA[(wv * 9 + i) << 9], aSrc[i] + kc);
#pragma unroll
        for (int j = 0; j < 6; ++j) {
            int g2 = wv * 6 + j;
            if (g2 < 22) llds16(&ldsB[g2 << 9], bSrc[j] + kc);
        }
        asm volatile("s_waitcnt vmcnt(0)" ::: "memory");
        __syncthreads();

#pragma unroll
        for (int kw = 0; kw < 3; ++kw) {
            bf16x8 bFr[4][2];
#pragma unroll
            for (int r = 0; r < 4; ++r)
#pragma unroll
                for (int half = 0; half < 2; ++half) {
                    int hi = (wv << 1) + r;
                    int wp = (half << 4) + n16 + kw;
                    bFr[r][half] = *(const bf16x8*)
                        &ldsB[(hi * 136 + (wp << 2) + q) << 3];
                }
#pragma unroll
            for (int kh = 0; kh < 3; ++kh) {
                int p = kh * 3 + kw;
                bf16x8 aF[4];
#pragma unroll
                for (int mt = 0; mt < 4; ++mt)
                    aF[mt] = *(const bf16x8*)&ldsA[((p << 8) + (mt << 6) + lane) << 3];
#pragma unroll
                for (int mt = 0; mt < 4; ++mt)
#pragma unroll
                    for (int nt = 0; nt < 4; ++nt)
                        acc[mt][nt] = __builtin_amdgcn_mfma_f32_16x16x32_bf16(
                            aF[mt], bFr[(nt >> 1) + kh][nt & 1], acc[mt][nt], 0, 0, 0);
            }
        }
        __syncthreads();
    }

    // epilogue: C/D layout col=lane&15 (spatial w), row=q*4+reg (c_out)
    if (stage == 1) {
#pragma unroll
        for (int mt = 0; mt < 4; ++mt) {
            int cb = co0 + (mt << 4) + (q << 2);
            f32x4 ss = *(const f32x4*)&sv[cb];
            f32x4 tt = *(const f32x4*)&tv[cb];
#pragma unroll
            for (int nt = 0; nt < 4; ++nt) {
                int h = h0 + (wv << 1) + (nt >> 1), w = ((nt & 1) << 4) + n16;
                ushort4 o;
                o.x = f2bf(fmaxf(acc[mt][nt][0] * ss[0] + tt[0], 0.f));
                o.y = f2bf(fmaxf(acc[mt][nt][1] * ss[1] + tt[1], 0.f));
                o.z = f2bf(fmaxf(acc[mt][nt][2] * ss[2] + tt[2], 0.f));
                o.w = f2bf(fmaxf(acc[mt][nt][3] * ss[3] + tt[3], 0.f));
                *(ushort4*)&ybf[(((nb << 5) + h) * 32 + w) * 256 + cb] = o;
            }
        }
    } else {
#pragma unroll
        for (int mt = 0; mt < 4; ++mt) {
            int cb = co0 + (mt << 4) + (q << 2);
            f32x4 ss = *(const f32x4*)&sv[cb];
            f32x4 tt = *(const f32x4*)&tv[cb];
#pragma unroll
            for (int nt = 0; nt < 4; ++nt) {
                int h = h0 + (wv << 1) + (nt >> 1), w = ((nt & 1) << 4) + n16;
#pragma unroll
                for (int j = 0; j < 4; ++j) {
                    int idx = (((nb << 8) + cb + j) << 10) + (h << 5) + w;
                    yf[idx] = fmaxf(acc[mt][nt][j] * ss[j] + tt[j] + skip[idx], 0.f);
                }
            }
        }
    }
}

extern "C" void kernel_launch(void* const* d_in, const int* in_sizes, int n_in,
                              void* d_out, int out_size, void* d_ws, size_t ws_size,
                              hipStream_t stream) {
    const float* x   = (const float*)d_in[0];
    const float* w1  = (const float*)d_in[1];
    const float* g1  = (const float*)d_in[2];
    const float* b1  = (const float*)d_in[3];
    const float* rm1 = (const float*)d_in[4];
    const float* rv1 = (const float*)d_in[5];
    const float* w2  = (const float*)d_in[6];
    const float* g2  = (const float*)d_in[7];
    const float* b2  = (const float*)d_in[8];
    const float* rm2 = (const float*)d_in[9];
    const float* rv2 = (const float*)d_in[10];

    char* ws = (char*)d_ws;
    u16*  XT  = (u16*)(ws);                    // 32 MB NHWC bf16 x
    u16*  H1  = (u16*)(ws + 33554432);         // 32 MB NHWC bf16 intermediate
    u16*  W1t = (u16*)(ws + 67108864);         // 1.18 MB
    u16*  W2t = (u16*)(ws + 68288512);         // 1.18 MB
    float* sc = (float*)(ws + 69468160);       // s1|t1|s2|t2, 256 f32 each
    u32*  zpg = (u32*)(ws + 69472256);         // 2 KB zeros
    if (ws_size < 69474304) return;            // workspace too small — bail

    prep<<<16896, 256, 0, stream>>>(x, XT, w1, w2, W1t, W2t,
                                    g1, b1, rm1, rv1, g2, b2, rm2, rv2,
                                    sc, zpg);

    conv_mfma<<<1024, 256, 0, stream>>>(XT, W1t, sc, sc + 256, nullptr,
                                        H1, nullptr, (const u16*)zpg, 1);
    conv_mfma<<<1024, 256, 0, stream>>>(H1, W2t, sc + 512, sc + 768, x,
                                        nullptr, (float*)d_out, (const u16*)zpg, 2);
}